// Round 1
// baseline (40.238 us; speedup 1.0000x reference)
//
#include <hip/hip_runtime.h>

#define BSZ 64
#define LMAX 128
#define DIM 2048

// ---------------- kernel 0: zero accumulators ----------------
__global__ void init_accum(float* accum, int* count) {
    accum[0] = 0.0f;
    count[0] = 0;
}

// ---------------- kernel 1: projections ----------------
// One wave (64 lanes) per position p in [0, BSZ*LMAX).
// Computes left0/left1 (h . W[:D, c]) and right0/right1 (h . W[D:, c]).
// Writes proj[p] = float4{l0, l1, r0, r1}.
__global__ __launch_bounds__(256) void proj_kernel(
        const float* __restrict__ enc,
        const float* __restrict__ W,
        float* __restrict__ proj) {
    const int wid  = threadIdx.x >> 6;
    const int lane = threadIdx.x & 63;
    const int p    = blockIdx.x * 4 + wid;   // position index

    const float4* h4 = (const float4*)(enc + (size_t)p * DIM);
    const float4* W4 = (const float4*)W;     // W is [2*DIM, 2] row-major

    float a0 = 0.f, a1 = 0.f, a2 = 0.f, a3 = 0.f;
    #pragma unroll
    for (int it = 0; it < 8; ++it) {
        const int idx = it * 64 + lane;      // float4 index within row, 0..511
        const float4 h = h4[idx];
        const int r = idx * 4;               // starting row of this chunk
        // left weights: floats W[r*2 .. r*2+7] -> float4 at r/2, r/2+1
        const float4 wa = W4[r / 2];
        const float4 wb = W4[r / 2 + 1];
        a0 += h.x * wa.x + h.y * wa.z + h.z * wb.x + h.w * wb.z;
        a1 += h.x * wa.y + h.y * wa.w + h.z * wb.y + h.w * wb.w;
        // right weights: offset DIM rows = DIM*2 floats = DIM/2 float4
        const float4 wc = W4[DIM / 2 + r / 2];
        const float4 wd = W4[DIM / 2 + r / 2 + 1];
        a2 += h.x * wc.x + h.y * wc.z + h.z * wd.x + h.w * wd.z;
        a3 += h.x * wc.y + h.y * wc.w + h.z * wd.y + h.w * wd.w;
    }
    // wave (64-lane) butterfly reduction
    #pragma unroll
    for (int off = 32; off >= 1; off >>= 1) {
        a0 += __shfl_xor(a0, off);
        a1 += __shfl_xor(a1, off);
        a2 += __shfl_xor(a2, off);
        a3 += __shfl_xor(a3, off);
    }
    if (lane == 0) {
        float4 o;
        o.x = a0; o.y = a1; o.z = a2; o.w = a3;
        ((float4*)proj)[p] = o;
    }
}

// ---------------- kernel 2: pairwise NLL reduction ----------------
// One block per batch. proj staged in LDS (2 KB), L*L validity loop.
__global__ __launch_bounds__(256) void loss_kernel(
        const int* __restrict__ mask,
        const float* __restrict__ proj,
        const float* __restrict__ bias,
        float* __restrict__ accum,
        int* __restrict__ count) {
    __shared__ float s_proj[LMAX * 4];
    __shared__ int   s_T;
    __shared__ float s_w[4];

    const int b   = blockIdx.x;
    const int tid = threadIdx.x;

    if (tid == 0) s_T = 0;
    __syncthreads();

    // stage projections for this batch
    for (int i = tid; i < LMAX * 4; i += 256)
        s_proj[i] = proj[b * LMAX * 4 + i];

    // turn length = sum of prefix mask
    if (tid < LMAX) {
        int m = mask[b * LMAX + tid];
        if (m) atomicAdd(&s_T, 1);
    }
    __syncthreads();

    const int   T  = s_T;
    const float b0 = bias[0];
    const float b1 = bias[1];

    float local = 0.f;
    for (int t = tid; t < LMAX * LMAX; t += 256) {
        const int j = t >> 7;          // / LMAX
        const int k = t & (LMAX - 1);  // % LMAX
        if (k < j && j < T) {
            const float l0 = s_proj[j * 4 + 0] + s_proj[k * 4 + 2] + b0;
            const float l1 = s_proj[j * 4 + 1] + s_proj[k * 4 + 3] + b1;
            const float mx  = fmaxf(l0, l1);
            const float lse = mx + logf(expf(l0 - mx) + expf(l1 - mx));
            const float chosen = (k == j - 1) ? l1 : l0;
            local += lse - chosen;
        }
    }

    // block reduce: wave butterfly then LDS
    #pragma unroll
    for (int off = 32; off >= 1; off >>= 1)
        local += __shfl_xor(local, off);
    if ((tid & 63) == 0) s_w[tid >> 6] = local;
    __syncthreads();
    if (tid == 0) {
        const float s = s_w[0] + s_w[1] + s_w[2] + s_w[3];
        atomicAdd(accum, s);
        atomicAdd(count, T * (T - 1) / 2);
    }
}

// ---------------- kernel 3: finalize ----------------
__global__ void finalize_kernel(const float* accum, const int* count, float* out) {
    const int c = count[0] > 1 ? count[0] : 1;
    out[0] = accum[0] / (float)c;
}

extern "C" void kernel_launch(void* const* d_in, const int* in_sizes, int n_in,
                              void* d_out, int out_size, void* d_ws, size_t ws_size,
                              hipStream_t stream) {
    const float* enc  = (const float*)d_in[0];  // [BSZ, LMAX, DIM] fp32
    const int*   mask = (const int*)d_in[1];    // [BSZ, LMAX] int32
    const float* W    = (const float*)d_in[2];  // [2*DIM, 2] fp32
    const float* bias = (const float*)d_in[3];  // [2] fp32
    float* out = (float*)d_out;

    // workspace layout: proj[BSZ*LMAX*4] floats, then accum (1 float), count (1 int)
    float* proj  = (float*)d_ws;
    float* accum = proj + BSZ * LMAX * 4;
    int*   count = (int*)(accum + 1);

    init_accum<<<1, 1, 0, stream>>>(accum, count);
    proj_kernel<<<(BSZ * LMAX) / 4, 256, 0, stream>>>(enc, W, proj);
    loss_kernel<<<BSZ, 256, 0, stream>>>(mask, proj, bias, accum, count);
    finalize_kernel<<<1, 1, 0, stream>>>(accum, count, out);
}